// Round 16
// baseline (1456.795 us; speedup 1.0000x reference)
//
#include <hip/hip_runtime.h>
#include <hip/hip_fp8.h>
#include <stdint.h>

// ---------------------------------------------------------------------------
// VQ-VAE quantizer. R16: coarse halves LDS traffic -- A operand lives in
// VGPRs with distance-2 prefetch (counted vmcnt(12), never drained mid-loop);
// B stays in LDS ring-3 (16KB slots, swizzled, gload_lds). L2-blocked
// traversal retained. Tail frozen from R15 (fused finish, gemms, prep).
// Sizes: M=B*T=16384, D=1024, K=8192 codes, H=512.
// ---------------------------------------------------------------------------

#define MROWS  16384
#define DDIM   1024
#define KCODES 8192
#define HDIM   512

typedef __attribute__((ext_vector_type(4))) float  f32x4;
typedef __attribute__((ext_vector_type(8))) __bf16 bf16x8;
typedef __attribute__((ext_vector_type(4))) int    i32x4;
typedef __attribute__((ext_vector_type(8))) int    i32x8;

__device__ __forceinline__ unsigned short f2bf(float f) {
  uint32_t b = __float_as_uint(f);
  b += 0x7FFFu + ((b >> 16) & 1u);          // RNE
  return (unsigned short)(b >> 16);
}

__device__ __forceinline__ uint32_t f2fp8(float f) {
  return (uint32_t)__hip_fp8_e4m3(f).__x;   // OCP e4m3fn, saturating
}

// sortable key: monotonic-f32 top 19 bits | idx (13 bits).
__device__ __forceinline__ uint32_t packkey(float s, int idx) {
  uint32_t u = __float_as_uint(s);
  u = ((int)u < 0) ? ~u : (u | 0x80000000u);
  return (u & 0xFFFFE000u) | (uint32_t)idx;
}
__device__ __forceinline__ float unpackkey(uint32_t k) {
  uint32_t u = k & 0xFFFFE000u;
  u = (u & 0x80000000u) ? (u ^ 0x80000000u) : ~u;
  return __uint_as_float(u);   // floor: result <= true score
}

__device__ __forceinline__ void gload_lds16(const void* g, void* l) {
  __builtin_amdgcn_global_load_lds(
      (__attribute__((address_space(1))) void*)(uintptr_t)g,
      (__attribute__((address_space(3))) void*)(uint32_t)(uintptr_t)l,
      16, 0, 0);
}

__device__ __forceinline__ f32x4 mfma_mx(i32x8 a, i32x8 b, f32x4 c) {
  return __builtin_amdgcn_mfma_scale_f32_16x16x128_f8f6f4(
      a, b, c, 0, 0, 0, 0x7F7F7F7F, 0, 0x7F7F7F7F);
}

__device__ __forceinline__ float waveReduceSum(float v) {
#pragma unroll
  for (int off = 32; off > 0; off >>= 1) v += __shfl_xor(v, off, 64);
  return v;
}

// ---------------------------------------------------------------------------
// K0: fused prep (frozen).
// ---------------------------------------------------------------------------
__global__ __launch_bounds__(256) void prep_kernel(
    const float* __restrict__ features, const float* __restrict__ codebook,
    const float* __restrict__ w1, const float* __restrict__ w2,
    uint8_t* __restrict__ xq8, uint8_t* __restrict__ cq8,
    unsigned short* __restrict__ cbb, float* __restrict__ cn,
    unsigned short* __restrict__ w1t, unsigned short* __restrict__ w2t) {
  __shared__ float wsum[4];
  __shared__ float tile[32][33];
  const int bid = blockIdx.x, t = threadIdx.x;
  if (bid < 8192) {
    const int id = bid * 256 + t;
    const float4 v0 = ((const float4*)features)[id * 2];
    const float4 v1 = ((const float4*)features)[id * 2 + 1];
    uint2 u;
    u.x = f2fp8(v0.x) | (f2fp8(v0.y) << 8) | (f2fp8(v0.z) << 16) |
          (f2fp8(v0.w) << 24);
    u.y = f2fp8(v1.x) | (f2fp8(v1.y) << 8) | (f2fp8(v1.z) << 16) |
          (f2fp8(v1.w) << 24);
    ((uint2*)xq8)[id] = u;
  } else if (bid < 16384) {
    const int k = bid - 8192;
    const float4 v = ((const float4*)(codebook + (size_t)k * DDIM))[t];
    ushort4 u;
    u.x = f2bf(v.x); u.y = f2bf(v.y); u.z = f2bf(v.z); u.w = f2bf(v.w);
    ((ushort4*)(cbb + (size_t)k * DDIM))[t] = u;
    const uint32_t p8 = f2fp8(v.x) | (f2fp8(v.y) << 8) | (f2fp8(v.z) << 16) |
                        (f2fp8(v.w) << 24);
    ((uint32_t*)(cq8 + (size_t)k * DDIM))[t] = p8;
    float p = v.x * v.x + v.y * v.y + v.z * v.z + v.w * v.w;
    p = waveReduceSum(p);
    if ((t & 63) == 0) wsum[t >> 6] = p;
    __syncthreads();
    if (t == 0) cn[k] = wsum[0] + wsum[1] + wsum[2] + wsum[3];
  } else {
    const float* src;
    unsigned short* dst;
    int R, C, t32;
    if (bid < 16896) { src = w1; dst = w1t; R = 1024; C = 512;
                       t32 = bid - 16384; }
    else             { src = w2; dst = w2t; R = 512;  C = 1024;
                       t32 = bid - 16896; }
    const int nct = C / 32;
    const int tr0 = (t32 / nct) * 32, tc0 = (t32 % nct) * 32;
    const int rr = t >> 3, cc = (t & 7) * 4;
    const float4 v = *(const float4*)(src + (size_t)(tr0 + rr) * C + tc0 + cc);
    tile[rr][cc + 0] = v.x; tile[rr][cc + 1] = v.y;
    tile[rr][cc + 2] = v.z; tile[rr][cc + 3] = v.w;
    __syncthreads();
    ushort4 o;
    o.x = f2bf(tile[cc + 0][rr]); o.y = f2bf(tile[cc + 1][rr]);
    o.z = f2bf(tile[cc + 2][rr]); o.w = f2bf(tile[cc + 3][rr]);
    *(ushort4*)(dst + (size_t)(tc0 + rr) * R + tr0 + cc) = o;
  }
}

// ---------------------------------------------------------------------------
// K4: coarse scores = cn[k] - 2 * (xq . cq) via MX-fp8 MFMA (K=128).
// 128x128 tile, 4 waves (2x2), 8 K-tiles, L2-blocked traversal.
// A: VGPR double-buffer, distance-2 prefetch (8 dwordx4/wave/KT, L2-hot).
// B: LDS ring-3 (3 x 16KB, swizzled byte^=((row&7)<<4), pre-swizzled src,
// gload_lds), distance-2 stage. Per KT: vmcnt(12) + s_barrier (never 0
// mid-loop; FIFO [B(kt+2) A(kt+2)] per KT). sched_barrier(0) pins all issues.
// Fold: packed keys -> LDS-transpose 2-phase -> cand2[row][nb] top-2 keys.
// ---------------------------------------------------------------------------
__global__ __launch_bounds__(256, 3) void coarse_kernel(
    const uint8_t* __restrict__ xq,   // [MROWS][DDIM] fp8
    const uint8_t* __restrict__ cq,   // [KCODES][DDIM] fp8
    const float* __restrict__ cn,     // [KCODES]
    uint32_t* __restrict__ cand2)     // [MROWS][64][2] keys
{
  __shared__ char smem[49152];   // B ring: 3 x 16KB; fold scratch 34.8KB alias

  const int tid = threadIdx.x;
  const int l = tid & 63, w = tid >> 6;
  const int lr = l & 15, lg = l >> 4;
  const int wm = w >> 1, wn = w & 1;

  // XCD assignment + L2-blocked order within XCD (4mb x 8nb chunks)
  const int bid = blockIdx.x;
  const int xcd = bid & 7;
  const int local = bid >> 3;            // 0..1023
  const int chunk = local >> 5;          // 0..31
  const int wi = local & 31;             // 0..31
  const int mb = xcd * 16 + (chunk >> 3) * 4 + (wi >> 3);   // 0..127
  const int nb = (chunk & 7) * 8 + (wi & 7);                // 0..63
  const int r0 = mb * 128, c0 = nb * 128;

  // B staging: linear LDS dest tid*16 + j*4096 in slot; chunk holds global
  // B-row (tid>>3)+j*32, col byte ((tid&7)*16) ^ ((row&7)<<4)
  const int scolb = ((tid & 7) * 16) ^ (((tid >> 3) & 7) << 4);
  const uint8_t* bSrc = cq + (size_t)(c0 + (tid >> 3)) * DDIM + scolb;
  const int dBase = tid * 16;

  // B fragment ds_read offsets (row&7 == lr&7)
  const int sxor = (lr & 7) << 4;
  const int kLo = (lg * 32) ^ sxor;
  const int kHi = (lg * 32 + 16) ^ sxor;
  const int bRow = (wn * 64 + lr) * 128;            // + ni*2048 + slot*16384

  // A direct: lane (lg,lr) reads row r0+wm*64+mi*16+lr, bytes kt*128+lg*32
  const uint8_t* aG = xq + (size_t)(r0 + wm * 64 + lr) * DDIM + lg * 32;

#define STAGE_B(KT, SLOT)                                                     \
  {                                                                           \
    char* sb = smem + (SLOT) * 16384;                                         \
    _Pragma("unroll")                                                         \
    for (int j = 0; j < 4; ++j)                                               \
      gload_lds16(bSrc + (size_t)j * 32 * DDIM + (KT) * 128,                  \
                  sb + dBase + j * 4096);                                     \
  }

#define LDB(dst, base, off)                                                   \
  {                                                                           \
    i32x4 _lo = *(const i32x4*)((base) + (off) + kLo);                        \
    i32x4 _hi = *(const i32x4*)((base) + (off) + kHi);                        \
    dst = __builtin_shufflevector(_lo, _hi, 0, 1, 2, 3, 4, 5, 6, 7);          \
  }

#define LDAG(dst, ptr)                                                        \
  {                                                                           \
    i32x4 _lo = *(const i32x4*)(ptr);                                         \
    i32x4 _hi = *(const i32x4*)((ptr) + 16);                                  \
    dst = __builtin_shufflevector(_lo, _hi, 0, 1, 2, 3, 4, 5, 6, 7);          \
  }

  f32x4 acc[4][4];
#pragma unroll
  for (int mi = 0; mi < 4; ++mi)
#pragma unroll
    for (int ni = 0; ni < 4; ++ni) acc[mi][ni] = 0.0f;

  i32x8 afE[4], afO[4];

  // prologue, pinned issue order: A0(8) B0(4) A1(8) B1(4)
  __builtin_amdgcn_sched_barrier(0);
#pragma unroll
  for (int mi = 0; mi < 4; ++mi)
    LDAG(afE[mi], aG + 0 * 128 + (size_t)mi * 16 * DDIM)
  __builtin_amdgcn_sched_barrier(0);
  STAGE_B(0, 0)
  __builtin_amdgcn_sched_barrier(0);
#pragma unroll
  for (int mi = 0; mi < 4; ++mi)
    LDAG(afO[mi], aG + 1 * 128 + (size_t)mi * 16 * DDIM)
  __builtin_amdgcn_sched_barrier(0);
  STAGE_B(1, 1)
  __builtin_amdgcn_sched_barrier(0);

// BODY(kt): wait B(kt)+A(kt) retired (vmcnt(12): leaves B(kt+1)+A(kt+1));
// barrier; stage B(kt+2); ds_read B(kt); MFMA with AFC=A(kt); reload AFC
// with A(kt+2). Per-KT issue stream = [B(kt+2) x4][A(kt+2) x8].
#define BODY(KT, AFC)                                                         \
  {                                                                           \
    const int kt_ = (KT);                                                     \
    const char* bb = smem + (kt_ % 3) * 16384;                                \
    __builtin_amdgcn_sched_barrier(0);                                        \
    if (kt_ == 7) { asm volatile("s_waitcnt vmcnt(0)" ::: "memory"); }        \
    else          { asm volatile("s_waitcnt vmcnt(12)" ::: "memory"); }       \
    __builtin_amdgcn_s_barrier();                                             \
    __builtin_amdgcn_sched_barrier(0);                                        \
    if (kt_ < 6) STAGE_B(kt_ + 2, (kt_ + 2) % 3)                              \
    __builtin_amdgcn_sched_barrier(0);                                        \
    i32x8 bf0, bf1;                                                           \
    LDB(bf0, bb, bRow + 0 * 2048)                                             \
    LDB(bf1, bb, bRow + 1 * 2048)                                             \
    __builtin_amdgcn_s_setprio(1);                                            \
    _Pragma("unroll")                                                         \
    for (int mi = 0; mi < 4; ++mi) {                                          \
      acc[mi][0] = mfma_mx(AFC[mi], bf0, acc[mi][0]);                         \
      acc[mi][1] = mfma_mx(AFC[mi], bf1, acc[mi][1]);                         \
    }                                                                         \
    __builtin_amdgcn_s_setprio(0);                                            \
    LDB(bf0, bb, bRow + 2 * 2048)                                             \
    LDB(bf1, bb, bRow + 3 * 2048)                                             \
    __builtin_amdgcn_s_setprio(1);                                            \
    _Pragma("unroll")                                                         \
    for (int mi = 0; mi < 4; ++mi) {                                          \
      acc[mi][2] = mfma_mx(AFC[mi], bf0, acc[mi][2]);                         \
      acc[mi][3] = mfma_mx(AFC[mi], bf1, acc[mi][3]);                         \
    }                                                                         \
    __builtin_amdgcn_s_setprio(0);                                            \
    __builtin_amdgcn_sched_barrier(0);                                        \
    if (kt_ < 6) {                                                            \
      _Pragma("unroll")                                                       \
      for (int mi = 0; mi < 4; ++mi)                                          \
        LDAG(AFC[mi], aG + (kt_ + 2) * 128 + (size_t)mi * 16 * DDIM)          \
    }                                                                         \
    __builtin_amdgcn_sched_barrier(0);                                        \
  }

#pragma unroll 1
  for (int kt2 = 0; kt2 < 4; ++kt2) {
    BODY(kt2 * 2,     afE)
    BODY(kt2 * 2 + 1, afO)
  }
  __syncthreads();   // ring dead; smem reused as fold scratch

  // ---- fold phase 1: per-lane key top-2 of 4 cols -> LDS [128][34] uint2 --
  uint2* mrg = (uint2*)smem;
  const int slot = wn * 16 + lr;

  float cnv[4];
#pragma unroll
  for (int ni = 0; ni < 4; ++ni) cnv[ni] = cn[c0 + wn * 64 + ni * 16 + lr];

#pragma unroll
  for (int mi = 0; mi < 4; ++mi) {
#pragma unroll
    for (int r = 0; r < 4; ++r) {
      uint32_t k1 = 0xFFFFFFFFu, k2 = 0xFFFFFFFFu;
#pragma unroll
      for (int ni = 0; ni < 4; ++ni) {
        const float s = fmaf(-2.0f, acc[mi][ni][r], cnv[ni]);
        const uint32_t k = packkey(s, c0 + wn * 64 + ni * 16 + lr);
        if (k < k1) { k2 = k1; k1 = k; } else if (k < k2) { k2 = k; }
      }
      const int row = wm * 64 + mi * 16 + lg * 4 + r;
      uint2 e; e.x = k1; e.y = k2;
      mrg[row * 34 + slot] = e;
    }
  }
  __syncthreads();

  // ---- fold phase 2: (row, half) thread scans 32 keys, cross-half merge ---
  {
    const int row = tid >> 1, h = tid & 1;
    const uint4* mp = (const uint4*)(mrg + row * 34 + h * 16);
    uint32_t k1 = 0xFFFFFFFFu, k2 = 0xFFFFFFFFu;
#pragma unroll
    for (int j = 0; j < 8; ++j) {
      const uint4 v = mp[j];
      uint32_t a = (k1 < v.x) ? k1 : v.x;
      uint32_t b0 = (k1 < v.x) ? v.x : k1;
      uint32_t c = (k2 < v.y) ? k2 : v.y;
      k1 = a; k2 = (b0 < c) ? b0 : c;
      a = (k1 < v.z) ? k1 : v.z;
      b0 = (k1 < v.z) ? v.z : k1;
      c = (k2 < v.w) ? k2 : v.w;
      k1 = a; k2 = (b0 < c) ? b0 : c;
    }
    const uint32_t o1 = (uint32_t)__shfl_xor((int)k1, 1, 64);
    const uint32_t o2 = (uint32_t)__shfl_xor((int)k2, 1, 64);
    const uint32_t m1 = (k1 < o1) ? k1 : o1;
    const uint32_t hi = (k1 < o1) ? o1 : k1;
    const uint32_t lo2 = (k2 < o2) ? k2 : o2;
    const uint32_t m2 = (hi < lo2) ? hi : lo2;
    if (h == 0) {
      uint2 o; o.x = m1; o.y = m2;
      *((uint2*)(cand2 + ((size_t)(r0 + row) * 64 + nb) * 2)) = o;
    }
  }
#undef STAGE_B
#undef LDB
#undef LDAG
#undef BODY
}

// ---------------------------------------------------------------------------
// K6/K7: bf16 GEMM C = A[M][K] * B[N][K]^T (+bias). EPI==1: relu->bf16.
// EPI==2: f32 store. (Frozen.)
// ---------------------------------------------------------------------------
template <int EPI>
__global__ __launch_bounds__(256) void gemm_bt_kernel(
    const unsigned short* __restrict__ A, const unsigned short* __restrict__ B,
    const float* __restrict__ bias, void* __restrict__ outp,
    int Nsize, int Kred, int nblk) {
  __shared__ unsigned short As[128 * 32];
  __shared__ unsigned short Bs[128 * 32];
  const int tid = threadIdx.x;
  const int l = tid & 63, w = tid >> 6;
  const int lr = l & 15, lg = l >> 4;
  const int wm = w >> 1, wn = w & 1;
  const int mb = blockIdx.x / nblk, nb = blockIdx.x % nblk;
  const int r0 = mb * 128, c0 = nb * 128;
  const int prow = tid >> 2, pcol = (tid & 3) * 8;

  f32x4 acc[4][4];
#pragma unroll
  for (int mi = 0; mi < 4; ++mi)
#pragma unroll
    for (int ni = 0; ni < 4; ++ni) acc[mi][ni] = 0.0f;

  const size_t aoff0 = (size_t)(r0 + prow) * Kred + pcol;
  const size_t aoff1 = aoff0 + (size_t)64 * Kred;
  const size_t boff0 = (size_t)(c0 + prow) * Kred + pcol;
  const size_t boff1 = boff0 + (size_t)64 * Kred;

  const int nks = Kred >> 5;
  for (int ks = 0; ks < nks; ++ks) {
    const int k0 = ks * 32;
    gload_lds16(A + aoff0 + k0, &As[tid * 8]);
    gload_lds16(A + aoff1 + k0, &As[2048 + tid * 8]);
    gload_lds16(B + boff0 + k0, &Bs[tid * 8]);
    gload_lds16(B + boff1 + k0, &Bs[2048 + tid * 8]);
    __syncthreads();

    bf16x8 af[4], bfv[4];
#pragma unroll
    for (int mi = 0; mi < 4; ++mi)
      af[mi] = *reinterpret_cast<const bf16x8*>(
          &As[(wm * 64 + mi * 16 + lr) * 32 + lg * 8]);
#pragma unroll
    for (int ni = 0; ni < 4; ++ni)
      bfv[ni] = *reinterpret_cast<const bf16x8*>(
          &Bs[(wn * 64 + ni * 16 + lr) * 32 + lg * 8]);
#pragma unroll
    for (int mi = 0; mi < 4; ++mi)
#pragma unroll
      for (int ni = 0; ni < 4; ++ni)
        acc[mi][ni] = __builtin_amdgcn_mfma_f32_16x16x32_bf16(
            af[mi], bfv[ni], acc[mi][ni], 0, 0, 0);
    __syncthreads();
  }

#pragma unroll
  for (int ni = 0; ni < 4; ++ni) {
    const int col = c0 + wn * 64 + ni * 16 + lr;
    const float bv = bias[col];
#pragma unroll
    for (int mi = 0; mi < 4; ++mi) {
#pragma unroll
      for (int r = 0; r < 4; ++r) {
        const int row = r0 + wm * 64 + mi * 16 + lg * 4 + r;
        const float v = acc[mi][ni][r] + bv;
        if (EPI == 1) {
          ((unsigned short*)outp)[(size_t)row * Nsize + col] =
              f2bf(fmaxf(v, 0.0f));
        } else {
          ((float*)outp)[(size_t)row * Nsize + col] = v;
        }
      }
    }
  }
}

// ---------------------------------------------------------------------------
// K5+K8 fused: top-select + exact fp32 rescore + recon gather + loss partial.
// One wave per row (4 rows/block). Margin 36 (validated). No atomics.
// ---------------------------------------------------------------------------
__global__ __launch_bounds__(256) void finish_kernel(
    const float* __restrict__ x, const float* __restrict__ cb,
    const float* __restrict__ dec, const uint32_t* __restrict__ cand2,
    float* __restrict__ out, float* __restrict__ partial) {
  __shared__ float wsum[4];
  const int wid = threadIdx.x >> 6;
  const int row = blockIdx.x * 4 + wid;
  const int l = threadIdx.x & 63;

  const uint2 pr = ((const uint2*)cand2)[(size_t)row * 64 + l];
  const uint32_t k1 = pr.x, k2 = pr.y;

  uint32_t bs = k1;
#pragma unroll
  for (int off = 1; off < 64; off <<= 1) {
    const uint32_t ob = (uint32_t)__shfl_xor((int)bs, off, 64);
    bs = (ob < bs) ? ob : bs;
  }
  const float smin = unpackkey(bs);
  const uint32_t thrkey = packkey(smin + 36.0f, 8191);
  unsigned long long mA = __ballot(k1 <= thrkey);
  unsigned long long mB = __ballot(k2 <= thrkey);

  int code;
  if (__popcll(mA) + __popcll(mB) == 1) {
    code = (int)(bs & 8191u);
  } else {
    const float4* x4 = (const float4*)(x + (size_t)row * DDIM);
    float4 xv[4];
#pragma unroll
    for (int i = 0; i < 4; ++i) xv[i] = x4[i * 64 + l];
    float bestS = __builtin_inff(); int bestI = KCODES;
#pragma unroll 1
    for (int half = 0; half < 2; ++half) {
      unsigned long long m = half ? mB : mA;
      const uint32_t myk = half ? k2 : k1;
      while (m) {
        const int b = __builtin_ctzll(m);
        m &= m - 1;
        const int cd = __shfl((int)myk, b, 64) & 8191;
        const float4* c4 = (const float4*)(cb + (size_t)cd * DDIM);
        float dot = 0.f, nn = 0.f;
#pragma unroll
        for (int i = 0; i < 4; ++i) {
          const float4 cv = c4[i * 64 + l];
          dot = fmaf(xv[i].x, cv.x, dot); dot = fmaf(xv[i].y, cv.y, dot);
          dot = fmaf(xv[i].z, cv.z, dot); dot = fmaf(xv[i].w, cv.w, dot);
          nn  = fmaf(cv.x, cv.x, nn);     nn  = fmaf(cv.y, cv.y, nn);
          nn  = fmaf(cv.z, cv.z, nn);     nn  = fmaf(cv.w, cv.w, nn);
        }
#pragma unroll
        for (int off = 32; off > 0; off >>= 1) {
          dot += __shfl_xor(dot, off, 64);
          nn  += __shfl_xor(nn,  off, 64);
        }
        const float sc = nn - 2.0f * dot;
        if (sc < bestS || (sc == bestS && cd < bestI)) { bestS = sc; bestI = cd; }
      }
    }
    code = bestI;
  }

  // recon gather + loss (all rows)
  const float4* d4 = (const float4*)(dec + (size_t)code * DDIM);
  const float4* x4 = (const float4*)(x + (size_t)row * DDIM);
  const float4* c4 = (const float4*)(cb + (size_t)code * DDIM);
  float4* o4 = (float4*)(out + (size_t)row * DDIM);
  float lsum = 0.0f;
#pragma unroll
  for (int i = 0; i < 4; ++i) {
    const float4 dv = d4[i * 64 + l];
    o4[i * 64 + l] = dv;
    const float4 xv = x4[i * 64 + l];
    const float4 cv = c4[i * 64 + l];
    const float ex = xv.x - cv.x, ey = xv.y - cv.y;
    const float ez = xv.z - cv.z, ew = xv.w - cv.w;
    lsum += ex * ex + ey * ey + ez * ez + ew * ew;
  }
  if (l == 0) out[(size_t)MROWS * DDIM + row] = (float)code;

  lsum = waveReduceSum(lsum);
  if (l == 0) wsum[wid] = lsum;
  __syncthreads();
  if (threadIdx.x == 0)
    partial[blockIdx.x] = wsum[0] + wsum[1] + wsum[2] + wsum[3];
}

// ---------------------------------------------------------------------------
// K9: deterministic final loss reduce over 4096 partials.
// ---------------------------------------------------------------------------
__global__ __launch_bounds__(256) void loss_reduce_kernel(
    const float* __restrict__ partial, float* __restrict__ out) {
  __shared__ float wsum[4];
  const int t = threadIdx.x;
  float s = 0.0f;
#pragma unroll
  for (int j = 0; j < 16; ++j) s += partial[t * 16 + j];
  s = waveReduceSum(s);
  if ((t & 63) == 0) wsum[t >> 6] = s;
  __syncthreads();
  if (t == 0) {
    const float total = wsum[0] + wsum[1] + wsum[2] + wsum[3];
    // 0.25 / 16777216 is a power-of-two scale: exact
    out[(size_t)MROWS * DDIM + MROWS] = total * (0.25f / 16777216.0f);
  }
}

// ---------------------------------------------------------------------------
extern "C" void kernel_launch(void* const* d_in, const int* in_sizes, int n_in,
                              void* d_out, int out_size, void* d_ws,
                              size_t ws_size, hipStream_t stream) {
  const float* features = (const float*)d_in[0];  // [8,2048,1024]
  const float* codebook = (const float*)d_in[1];  // [8192,1024]
  const float* w1 = (const float*)d_in[2];        // [1024,512]
  const float* b1 = (const float*)d_in[3];        // [512]
  const float* w2 = (const float*)d_in[4];        // [512,1024]
  const float* b2 = (const float*)d_in[5];        // [1024]
  float* out = (float*)d_out;
  char* ws = (char*)d_ws;

  uint8_t*        xq8 = (uint8_t*)(ws + 0);                // 16,777,216
  uint8_t*        cq8 = (uint8_t*)(ws + 16777216);         //  8,388,608
  unsigned short* cbb = (unsigned short*)(ws + 25165824);  // 16,777,216
  float*          cn  = (float*)(ws + 41943040);           //     32,768
  unsigned short* w1t = (unsigned short*)(ws + 41975808);  //  1,048,576
  unsigned short* w2t = (unsigned short*)(ws + 43024384);  //  1,048,576
  unsigned short* hb  = (unsigned short*)(ws + 44072960);  //  8,388,608
  float*          dec = (float*)(ws + 52461568);           // 33,554,432
  float*          lpart = (float*)(ws + 86016000);         //     16,384
  uint32_t*       cand2 = (uint32_t*)(ws + 86032384);      //  8,388,608
  // total 94,420,992 bytes

  prep_kernel<<<17408, 256, 0, stream>>>(features, codebook, w1, w2,
                                         xq8, cq8, cbb, cn, w1t, w2t);

  coarse_kernel<<<(MROWS / 128) * (KCODES / 128), 256, 0, stream>>>(
      xq8, cq8, cn, cand2);

  // decode the codebook (8192 rows); cand2 consumed by finish afterwards
  gemm_bt_kernel<1><<<64 * (HDIM / 128), 256, 0, stream>>>(
      cbb, w1t, b1, hb, HDIM, DDIM, HDIM / 128);
  gemm_bt_kernel<2><<<64 * (DDIM / 128), 256, 0, stream>>>(
      hb, w2t, b2, dec, DDIM, HDIM, DDIM / 128);

  finish_kernel<<<MROWS / 4, 256, 0, stream>>>(features, codebook, dec,
                                               cand2, out, lpart);
  loss_reduce_kernel<<<1, 256, 0, stream>>>(lpart, out);
}

// Round 17
// 304.840 us; speedup vs baseline: 4.7789x; 4.7789x over previous
//
#include <hip/hip_runtime.h>
#include <hip/hip_fp8.h>
#include <stdint.h>

// ---------------------------------------------------------------------------
// VQ-VAE quantizer. R17 = R15 exact revert (best validated, 306 us).
// R16's A-in-VGPR double-buffer spilled to scratch (WRITE 4GB) -- third
// falsification of A-direct; permanently dead lever.
// coarse: MX-fp8 K=128, 128x128 tile, 4 waves, A+B in LDS 32KB,
// L2-blocked traversal, 3 blocks/CU. Tail: fused finish, no atomics.
// Sizes: M=B*T=16384, D=1024, K=8192 codes, H=512.
// ---------------------------------------------------------------------------

#define MROWS  16384
#define DDIM   1024
#define KCODES 8192
#define HDIM   512

typedef __attribute__((ext_vector_type(4))) float  f32x4;
typedef __attribute__((ext_vector_type(8))) __bf16 bf16x8;
typedef __attribute__((ext_vector_type(4))) int    i32x4;
typedef __attribute__((ext_vector_type(8))) int    i32x8;

__device__ __forceinline__ unsigned short f2bf(float f) {
  uint32_t b = __float_as_uint(f);
  b += 0x7FFFu + ((b >> 16) & 1u);          // RNE
  return (unsigned short)(b >> 16);
}

__device__ __forceinline__ uint32_t f2fp8(float f) {
  return (uint32_t)__hip_fp8_e4m3(f).__x;   // OCP e4m3fn, saturating
}

// sortable key: monotonic-f32 top 19 bits | idx (13 bits).
__device__ __forceinline__ uint32_t packkey(float s, int idx) {
  uint32_t u = __float_as_uint(s);
  u = ((int)u < 0) ? ~u : (u | 0x80000000u);
  return (u & 0xFFFFE000u) | (uint32_t)idx;
}
__device__ __forceinline__ float unpackkey(uint32_t k) {
  uint32_t u = k & 0xFFFFE000u;
  u = (u & 0x80000000u) ? (u ^ 0x80000000u) : ~u;
  return __uint_as_float(u);   // floor: result <= true score
}

__device__ __forceinline__ void gload_lds16(const void* g, void* l) {
  __builtin_amdgcn_global_load_lds(
      (__attribute__((address_space(1))) void*)(uintptr_t)g,
      (__attribute__((address_space(3))) void*)(uint32_t)(uintptr_t)l,
      16, 0, 0);
}

__device__ __forceinline__ f32x4 mfma_mx(i32x8 a, i32x8 b, f32x4 c) {
  return __builtin_amdgcn_mfma_scale_f32_16x16x128_f8f6f4(
      a, b, c, 0, 0, 0, 0x7F7F7F7F, 0, 0x7F7F7F7F);
}

__device__ __forceinline__ float waveReduceSum(float v) {
#pragma unroll
  for (int off = 32; off > 0; off >>= 1) v += __shfl_xor(v, off, 64);
  return v;
}

// ---------------------------------------------------------------------------
// K0: fused prep.
// ---------------------------------------------------------------------------
__global__ __launch_bounds__(256) void prep_kernel(
    const float* __restrict__ features, const float* __restrict__ codebook,
    const float* __restrict__ w1, const float* __restrict__ w2,
    uint8_t* __restrict__ xq8, uint8_t* __restrict__ cq8,
    unsigned short* __restrict__ cbb, float* __restrict__ cn,
    unsigned short* __restrict__ w1t, unsigned short* __restrict__ w2t) {
  __shared__ float wsum[4];
  __shared__ float tile[32][33];
  const int bid = blockIdx.x, t = threadIdx.x;
  if (bid < 8192) {
    const int id = bid * 256 + t;
    const float4 v0 = ((const float4*)features)[id * 2];
    const float4 v1 = ((const float4*)features)[id * 2 + 1];
    uint2 u;
    u.x = f2fp8(v0.x) | (f2fp8(v0.y) << 8) | (f2fp8(v0.z) << 16) |
          (f2fp8(v0.w) << 24);
    u.y = f2fp8(v1.x) | (f2fp8(v1.y) << 8) | (f2fp8(v1.z) << 16) |
          (f2fp8(v1.w) << 24);
    ((uint2*)xq8)[id] = u;
  } else if (bid < 16384) {
    const int k = bid - 8192;
    const float4 v = ((const float4*)(codebook + (size_t)k * DDIM))[t];
    ushort4 u;
    u.x = f2bf(v.x); u.y = f2bf(v.y); u.z = f2bf(v.z); u.w = f2bf(v.w);
    ((ushort4*)(cbb + (size_t)k * DDIM))[t] = u;
    const uint32_t p8 = f2fp8(v.x) | (f2fp8(v.y) << 8) | (f2fp8(v.z) << 16) |
                        (f2fp8(v.w) << 24);
    ((uint32_t*)(cq8 + (size_t)k * DDIM))[t] = p8;
    float p = v.x * v.x + v.y * v.y + v.z * v.z + v.w * v.w;
    p = waveReduceSum(p);
    if ((t & 63) == 0) wsum[t >> 6] = p;
    __syncthreads();
    if (t == 0) cn[k] = wsum[0] + wsum[1] + wsum[2] + wsum[3];
  } else {
    const float* src;
    unsigned short* dst;
    int R, C, t32;
    if (bid < 16896) { src = w1; dst = w1t; R = 1024; C = 512;
                       t32 = bid - 16384; }
    else             { src = w2; dst = w2t; R = 512;  C = 1024;
                       t32 = bid - 16896; }
    const int nct = C / 32;
    const int tr0 = (t32 / nct) * 32, tc0 = (t32 % nct) * 32;
    const int rr = t >> 3, cc = (t & 7) * 4;
    const float4 v = *(const float4*)(src + (size_t)(tr0 + rr) * C + tc0 + cc);
    tile[rr][cc + 0] = v.x; tile[rr][cc + 1] = v.y;
    tile[rr][cc + 2] = v.z; tile[rr][cc + 3] = v.w;
    __syncthreads();
    ushort4 o;
    o.x = f2bf(tile[cc + 0][rr]); o.y = f2bf(tile[cc + 1][rr]);
    o.z = f2bf(tile[cc + 2][rr]); o.w = f2bf(tile[cc + 3][rr]);
    *(ushort4*)(dst + (size_t)(tc0 + rr) * R + tr0 + cc) = o;
  }
}

// ---------------------------------------------------------------------------
// K4: coarse (R13/R15 exact). 128x128 tile, 4 waves, 8 K-tiles, A+B in LDS
// 32KB, L2-blocked traversal (4mb x 8nb chunks/XCD). Fold: packed keys ->
// LDS-transpose 2-phase -> cand2[row][nb] top-2 keys.
// ---------------------------------------------------------------------------
__global__ __launch_bounds__(256, 3) void coarse_kernel(
    const uint8_t* __restrict__ xq,   // [MROWS][DDIM] fp8
    const uint8_t* __restrict__ cq,   // [KCODES][DDIM] fp8
    const float* __restrict__ cn,     // [KCODES]
    uint32_t* __restrict__ cand2)     // [MROWS][64][2] keys
{
  __shared__ char smem[34816];   // main: 32KB (A16+B16); fold: 128x34 uint2

  const int tid = threadIdx.x;
  const int l = tid & 63, w = tid >> 6;
  const int lr = l & 15, lg = l >> 4;
  const int wm = w >> 1, wn = w & 1;

  // XCD assignment + L2-blocked order within XCD (4mb x 8nb chunks)
  const int bid = blockIdx.x;
  const int xcd = bid & 7;
  const int local = bid >> 3;            // 0..1023
  const int chunk = local >> 5;          // 0..31
  const int wi = local & 31;             // 0..31
  const int mb = xcd * 16 + (chunk >> 3) * 4 + (wi >> 3);   // 0..127
  const int nb = (chunk & 7) * 8 + (wi & 7);                // 0..63
  const int r0 = mb * 128, c0 = nb * 128;

  const int scolb = ((tid & 7) * 16) ^ (((tid >> 3) & 7) << 4);
  const uint8_t* aSrc = xq + (size_t)(r0 + (tid >> 3)) * DDIM + scolb;
  const uint8_t* bSrc = cq + (size_t)(c0 + (tid >> 3)) * DDIM + scolb;
  const int dBase = tid * 16;

  const int sxor = (lr & 7) << 4;
  const int kLo = (lg * 32) ^ sxor;
  const int kHi = (lg * 32 + 16) ^ sxor;
  const int aRow = (wm * 64 + lr) * 128;            // + mi*2048
  const int bRow = 16384 + (wn * 64 + lr) * 128;    // + ni*2048

#define STAGE(KT)                                                             \
  {                                                                           \
    _Pragma("unroll")                                                         \
    for (int j = 0; j < 4; ++j)                                               \
      gload_lds16(aSrc + (size_t)j * 32 * DDIM + (KT) * 128,                  \
                  smem + dBase + j * 4096);                                   \
    _Pragma("unroll")                                                         \
    for (int j = 0; j < 4; ++j)                                               \
      gload_lds16(bSrc + (size_t)j * 32 * DDIM + (KT) * 128,                  \
                  smem + 16384 + dBase + j * 4096);                           \
  }

#define LDFRAG(dst, off)                                                      \
  {                                                                           \
    i32x4 _lo = *(const i32x4*)(smem + (off) + kLo);                          \
    i32x4 _hi = *(const i32x4*)(smem + (off) + kHi);                          \
    dst = __builtin_shufflevector(_lo, _hi, 0, 1, 2, 3, 4, 5, 6, 7);          \
  }

  f32x4 acc[4][4];
#pragma unroll
  for (int mi = 0; mi < 4; ++mi)
#pragma unroll
    for (int ni = 0; ni < 4; ++ni) acc[mi][ni] = 0.0f;

#pragma unroll 1
  for (int kt = 0; kt < 8; ++kt) {
    __builtin_amdgcn_sched_barrier(0);
    STAGE(kt)
    __builtin_amdgcn_sched_barrier(0);
    __syncthreads();                        // loads landed (vmcnt drained)

    i32x8 bf[4];
#pragma unroll
    for (int ni = 0; ni < 4; ++ni) LDFRAG(bf[ni], bRow + ni * 2048)
#pragma unroll
    for (int mi = 0; mi < 4; ++mi) {
      i32x8 af;
      LDFRAG(af, aRow + mi * 2048)
      __builtin_amdgcn_s_setprio(1);
#pragma unroll
      for (int ni = 0; ni < 4; ++ni)
        acc[mi][ni] = mfma_mx(af, bf[ni], acc[mi][ni]);
      __builtin_amdgcn_s_setprio(0);
    }

    __builtin_amdgcn_sched_barrier(0);      // no ds_read may sink below
    __syncthreads();                        // all reads done; buffer free
  }

  // ---- fold phase 1: per-lane key top-2 of 4 cols -> LDS [128][34] uint2 --
  uint2* mrg = (uint2*)smem;
  const int slot = wn * 16 + lr;

  float cnv[4];
#pragma unroll
  for (int ni = 0; ni < 4; ++ni) cnv[ni] = cn[c0 + wn * 64 + ni * 16 + lr];

#pragma unroll
  for (int mi = 0; mi < 4; ++mi) {
#pragma unroll
    for (int r = 0; r < 4; ++r) {
      uint32_t k1 = 0xFFFFFFFFu, k2 = 0xFFFFFFFFu;
#pragma unroll
      for (int ni = 0; ni < 4; ++ni) {
        const float s = fmaf(-2.0f, acc[mi][ni][r], cnv[ni]);
        const uint32_t k = packkey(s, c0 + wn * 64 + ni * 16 + lr);
        if (k < k1) { k2 = k1; k1 = k; } else if (k < k2) { k2 = k; }
      }
      const int row = wm * 64 + mi * 16 + lg * 4 + r;
      uint2 e; e.x = k1; e.y = k2;
      mrg[row * 34 + slot] = e;
    }
  }
  __syncthreads();

  // ---- fold phase 2: (row, half) thread scans 32 keys, cross-half merge ---
  {
    const int row = tid >> 1, h = tid & 1;
    const uint4* mp = (const uint4*)(mrg + row * 34 + h * 16);
    uint32_t k1 = 0xFFFFFFFFu, k2 = 0xFFFFFFFFu;
#pragma unroll
    for (int j = 0; j < 8; ++j) {
      const uint4 v = mp[j];
      uint32_t a = (k1 < v.x) ? k1 : v.x;
      uint32_t b0 = (k1 < v.x) ? v.x : k1;
      uint32_t c = (k2 < v.y) ? k2 : v.y;
      k1 = a; k2 = (b0 < c) ? b0 : c;
      a = (k1 < v.z) ? k1 : v.z;
      b0 = (k1 < v.z) ? v.z : k1;
      c = (k2 < v.w) ? k2 : v.w;
      k1 = a; k2 = (b0 < c) ? b0 : c;
    }
    const uint32_t o1 = (uint32_t)__shfl_xor((int)k1, 1, 64);
    const uint32_t o2 = (uint32_t)__shfl_xor((int)k2, 1, 64);
    const uint32_t m1 = (k1 < o1) ? k1 : o1;
    const uint32_t hi = (k1 < o1) ? o1 : k1;
    const uint32_t lo2 = (k2 < o2) ? k2 : o2;
    const uint32_t m2 = (hi < lo2) ? hi : lo2;
    if (h == 0) {
      uint2 o; o.x = m1; o.y = m2;
      *((uint2*)(cand2 + ((size_t)(r0 + row) * 64 + nb) * 2)) = o;
    }
  }
#undef STAGE
#undef LDFRAG
}

// ---------------------------------------------------------------------------
// K6/K7: bf16 GEMM C = A[M][K] * B[N][K]^T (+bias). EPI==1: relu->bf16.
// EPI==2: f32 store.
// ---------------------------------------------------------------------------
template <int EPI>
__global__ __launch_bounds__(256) void gemm_bt_kernel(
    const unsigned short* __restrict__ A, const unsigned short* __restrict__ B,
    const float* __restrict__ bias, void* __restrict__ outp,
    int Nsize, int Kred, int nblk) {
  __shared__ unsigned short As[128 * 32];
  __shared__ unsigned short Bs[128 * 32];
  const int tid = threadIdx.x;
  const int l = tid & 63, w = tid >> 6;
  const int lr = l & 15, lg = l >> 4;
  const int wm = w >> 1, wn = w & 1;
  const int mb = blockIdx.x / nblk, nb = blockIdx.x % nblk;
  const int r0 = mb * 128, c0 = nb * 128;
  const int prow = tid >> 2, pcol = (tid & 3) * 8;

  f32x4 acc[4][4];
#pragma unroll
  for (int mi = 0; mi < 4; ++mi)
#pragma unroll
    for (int ni = 0; ni < 4; ++ni) acc[mi][ni] = 0.0f;

  const size_t aoff0 = (size_t)(r0 + prow) * Kred + pcol;
  const size_t aoff1 = aoff0 + (size_t)64 * Kred;
  const size_t boff0 = (size_t)(c0 + prow) * Kred + pcol;
  const size_t boff1 = boff0 + (size_t)64 * Kred;

  const int nks = Kred >> 5;
  for (int ks = 0; ks < nks; ++ks) {
    const int k0 = ks * 32;
    gload_lds16(A + aoff0 + k0, &As[tid * 8]);
    gload_lds16(A + aoff1 + k0, &As[2048 + tid * 8]);
    gload_lds16(B + boff0 + k0, &Bs[tid * 8]);
    gload_lds16(B + boff1 + k0, &Bs[2048 + tid * 8]);
    __syncthreads();

    bf16x8 af[4], bfv[4];
#pragma unroll
    for (int mi = 0; mi < 4; ++mi)
      af[mi] = *reinterpret_cast<const bf16x8*>(
          &As[(wm * 64 + mi * 16 + lr) * 32 + lg * 8]);
#pragma unroll
    for (int ni = 0; ni < 4; ++ni)
      bfv[ni] = *reinterpret_cast<const bf16x8*>(
          &Bs[(wn * 64 + ni * 16 + lr) * 32 + lg * 8]);
#pragma unroll
    for (int mi = 0; mi < 4; ++mi)
#pragma unroll
      for (int ni = 0; ni < 4; ++ni)
        acc[mi][ni] = __builtin_amdgcn_mfma_f32_16x16x32_bf16(
            af[mi], bfv[ni], acc[mi][ni], 0, 0, 0);
    __syncthreads();
  }

#pragma unroll
  for (int ni = 0; ni < 4; ++ni) {
    const int col = c0 + wn * 64 + ni * 16 + lr;
    const float bv = bias[col];
#pragma unroll
    for (int mi = 0; mi < 4; ++mi) {
#pragma unroll
      for (int r = 0; r < 4; ++r) {
        const int row = r0 + wm * 64 + mi * 16 + lg * 4 + r;
        const float v = acc[mi][ni][r] + bv;
        if (EPI == 1) {
          ((unsigned short*)outp)[(size_t)row * Nsize + col] =
              f2bf(fmaxf(v, 0.0f));
        } else {
          ((float*)outp)[(size_t)row * Nsize + col] = v;
        }
      }
    }
  }
}

// ---------------------------------------------------------------------------
// K5+K8 fused: top-select + exact fp32 rescore + recon gather + loss partial.
// One wave per row (4 rows/block). Margin 36 (validated). No atomics.
// ---------------------------------------------------------------------------
__global__ __launch_bounds__(256) void finish_kernel(
    const float* __restrict__ x, const float* __restrict__ cb,
    const float* __restrict__ dec, const uint32_t* __restrict__ cand2,
    float* __restrict__ out, float* __restrict__ partial) {
  __shared__ float wsum[4];
  const int wid = threadIdx.x >> 6;
  const int row = blockIdx.x * 4 + wid;
  const int l = threadIdx.x & 63;

  const uint2 pr = ((const uint2*)cand2)[(size_t)row * 64 + l];
  const uint32_t k1 = pr.x, k2 = pr.y;

  uint32_t bs = k1;
#pragma unroll
  for (int off = 1; off < 64; off <<= 1) {
    const uint32_t ob = (uint32_t)__shfl_xor((int)bs, off, 64);
    bs = (ob < bs) ? ob : bs;
  }
  const float smin = unpackkey(bs);
  const uint32_t thrkey = packkey(smin + 36.0f, 8191);
  unsigned long long mA = __ballot(k1 <= thrkey);
  unsigned long long mB = __ballot(k2 <= thrkey);

  int code;
  if (__popcll(mA) + __popcll(mB) == 1) {
    code = (int)(bs & 8191u);
  } else {
    const float4* x4 = (const float4*)(x + (size_t)row * DDIM);
    float4 xv[4];
#pragma unroll
    for (int i = 0; i < 4; ++i) xv[i] = x4[i * 64 + l];
    float bestS = __builtin_inff(); int bestI = KCODES;
#pragma unroll 1
    for (int half = 0; half < 2; ++half) {
      unsigned long long m = half ? mB : mA;
      const uint32_t myk = half ? k2 : k1;
      while (m) {
        const int b = __builtin_ctzll(m);
        m &= m - 1;
        const int cd = __shfl((int)myk, b, 64) & 8191;
        const float4* c4 = (const float4*)(cb + (size_t)cd * DDIM);
        float dot = 0.f, nn = 0.f;
#pragma unroll
        for (int i = 0; i < 4; ++i) {
          const float4 cv = c4[i * 64 + l];
          dot = fmaf(xv[i].x, cv.x, dot); dot = fmaf(xv[i].y, cv.y, dot);
          dot = fmaf(xv[i].z, cv.z, dot); dot = fmaf(xv[i].w, cv.w, dot);
          nn  = fmaf(cv.x, cv.x, nn);     nn  = fmaf(cv.y, cv.y, nn);
          nn  = fmaf(cv.z, cv.z, nn);     nn  = fmaf(cv.w, cv.w, nn);
        }
#pragma unroll
        for (int off = 32; off > 0; off >>= 1) {
          dot += __shfl_xor(dot, off, 64);
          nn  += __shfl_xor(nn,  off, 64);
        }
        const float sc = nn - 2.0f * dot;
        if (sc < bestS || (sc == bestS && cd < bestI)) { bestS = sc; bestI = cd; }
      }
    }
    code = bestI;
  }

  // recon gather + loss (all rows)
  const float4* d4 = (const float4*)(dec + (size_t)code * DDIM);
  const float4* x4 = (const float4*)(x + (size_t)row * DDIM);
  const float4* c4 = (const float4*)(cb + (size_t)code * DDIM);
  float4* o4 = (float4*)(out + (size_t)row * DDIM);
  float lsum = 0.0f;
#pragma unroll
  for (int i = 0; i < 4; ++i) {
    const float4 dv = d4[i * 64 + l];
    o4[i * 64 + l] = dv;
    const float4 xv = x4[i * 64 + l];
    const float4 cv = c4[i * 64 + l];
    const float ex = xv.x - cv.x, ey = xv.y - cv.y;
    const float ez = xv.z - cv.z, ew = xv.w - cv.w;
    lsum += ex * ex + ey * ey + ez * ez + ew * ew;
  }
  if (l == 0) out[(size_t)MROWS * DDIM + row] = (float)code;

  lsum = waveReduceSum(lsum);
  if (l == 0) wsum[wid] = lsum;
  __syncthreads();
  if (threadIdx.x == 0)
    partial[blockIdx.x] = wsum[0] + wsum[1] + wsum[2] + wsum[3];
}

// ---------------------------------------------------------------------------
// K9: deterministic final loss reduce over 4096 partials.
// ---------------------------------------------------------------------------
__global__ __launch_bounds__(256) void loss_reduce_kernel(
    const float* __restrict__ partial, float* __restrict__ out) {
  __shared__ float wsum[4];
  const int t = threadIdx.x;
  float s = 0.0f;
#pragma unroll
  for (int j = 0; j < 16; ++j) s += partial[t * 16 + j];
  s = waveReduceSum(s);
  if ((t & 63) == 0) wsum[t >> 6] = s;
  __syncthreads();
  if (t == 0) {
    const float total = wsum[0] + wsum[1] + wsum[2] + wsum[3];
    // 0.25 / 16777216 is a power-of-two scale: exact
    out[(size_t)MROWS * DDIM + MROWS] = total * (0.25f / 16777216.0f);
  }
}

// ---------------------------------------------------------------------------
extern "C" void kernel_launch(void* const* d_in, const int* in_sizes, int n_in,
                              void* d_out, int out_size, void* d_ws,
                              size_t ws_size, hipStream_t stream) {
  const float* features = (const float*)d_in[0];  // [8,2048,1024]
  const float* codebook = (const float*)d_in[1];  // [8192,1024]
  const float* w1 = (const float*)d_in[2];        // [1024,512]
  const float* b1 = (const float*)d_in[3];        // [512]
  const float* w2 = (const float*)d_in[4];        // [512,1024]
  const float* b2 = (const float*)d_in[5];        // [1024]
  float* out = (float*)d_out;
  char* ws = (char*)d_ws;

  uint8_t*        xq8 = (uint8_t*)(ws + 0);                // 16,777,216
  uint8_t*        cq8 = (uint8_t*)(ws + 16777216);         //  8,388,608
  unsigned short* cbb = (unsigned short*)(ws + 25165824);  // 16,777,216
  float*          cn  = (float*)(ws + 41943040);           //     32,768
  unsigned short* w1t = (unsigned short*)(ws + 41975808);  //  1,048,576
  unsigned short* w2t = (unsigned short*)(ws + 43024384);  //  1,048,576
  unsigned short* hb  = (unsigned short*)(ws + 44072960);  //  8,388,608
  float*          dec = (float*)(ws + 52461568);           // 33,554,432
  float*          lpart = (float*)(ws + 86016000);         //     16,384
  uint32_t*       cand2 = (uint32_t*)(ws + 86032384);      //  8,388,608
  // total 94,420,992 bytes

  prep_kernel<<<17408, 256, 0, stream>>>(features, codebook, w1, w2,
                                         xq8, cq8, cbb, cn, w1t, w2t);

  coarse_kernel<<<(MROWS / 128) * (KCODES / 128), 256, 0, stream>>>(
      xq8, cq8, cn, cand2);

  // decode the codebook (8192 rows); cand2 consumed by finish afterwards
  gemm_bt_kernel<1><<<64 * (HDIM / 128), 256, 0, stream>>>(
      cbb, w1t, b1, hb, HDIM, DDIM, HDIM / 128);
  gemm_bt_kernel<2><<<64 * (DDIM / 128), 256, 0, stream>>>(
      hb, w2t, b2, dec, DDIM, HDIM, DDIM / 128);

  finish_kernel<<<MROWS / 4, 256, 0, stream>>>(features, codebook, dec,
                                               cand2, out, lpart);
  loss_reduce_kernel<<<1, 256, 0, stream>>>(lpart, out);
}